// Round 10
// baseline (1117.984 us; speedup 1.0000x reference)
//
#include <hip/hip_runtime.h>

#define DIV_UP(a,b) (((a)+(b)-1)/(b))

// ---------- ordered-uint float max keys ----------
__device__ __forceinline__ unsigned f2key(float f) {
  unsigned u = __float_as_uint(f);
  return (u & 0x80000000u) ? ~u : (u | 0x80000000u);
}
__device__ __forceinline__ float key2f(unsigned u) {
  unsigned b = (u & 0x80000000u) ? (u ^ 0x80000000u) : ~u;
  return __uint_as_float(b);
}

// ---------- bf16 pack/unpack (RNE) ----------
__device__ __forceinline__ unsigned short f2bf(float f) {
  unsigned u = __float_as_uint(f);
  unsigned r = u + 0x7FFFu + ((u >> 16) & 1u);
  return (unsigned short)(r >> 16);
}
__device__ __forceinline__ float bf2f(unsigned short s) {
  return __uint_as_float(((unsigned)s) << 16);
}

// ---------- utility ----------
__global__ void k_zero(int* p, int n) {
  int i = blockIdx.x * blockDim.x + threadIdx.x;
  if (i < n) p[i] = 0;
}

// ---------- degree count ----------
__global__ void k_count(const int* __restrict__ row, int* __restrict__ cnt, int E) {
  int e = blockIdx.x * blockDim.x + threadIdx.x;
  if (e < E) atomicAdd(&cnt[row[e]], 1);
}

__global__ void k_dis(const int* __restrict__ cnt, float* __restrict__ dis, int N) {
  int i = blockIdx.x * blockDim.x + threadIdx.x;
  if (i < N) {
    int c = cnt[i];
    dis[i] = (c > 0) ? rsqrtf((float)c) : 0.0f;
  }
}

// ---------- 3-kernel exclusive scan over cnt -> rowptr ----------
__global__ void k_scan1(const int* __restrict__ cnt, int* __restrict__ incl,
                        int* __restrict__ bsum, int N) {
  __shared__ int s[1024];
  int t = threadIdx.x;
  int i = blockIdx.x * 1024 + t;
  int v = (i < N) ? cnt[i] : 0;
  s[t] = v;
  __syncthreads();
  for (int off = 1; off < 1024; off <<= 1) {
    int add = (t >= off) ? s[t - off] : 0;
    __syncthreads();
    s[t] += add;
    __syncthreads();
  }
  if (i < N) incl[i] = s[t];
  if (t == 1023) bsum[blockIdx.x] = s[1023];
}

__global__ void k_scan2(const int* __restrict__ bsum, int* __restrict__ bex, int nb) {
  if (threadIdx.x == 0) {
    int run = 0;
    for (int b = 0; b < nb; ++b) { bex[b] = run; run += bsum[b]; }
  }
}

__global__ void k_scan3(const int* __restrict__ incl, const int* __restrict__ cnt,
                        const int* __restrict__ bex, int* __restrict__ rowptr,
                        int* __restrict__ cursor, int N, int E) {
  int i = blockIdx.x * blockDim.x + threadIdx.x;
  if (i < N) {
    int v = incl[i] - cnt[i] + bex[i >> 10];
    rowptr[i] = v;
    cursor[i] = v;
  }
  if (i == 0) rowptr[N] = E;
}

// ---------- CSR fill: col only, non-temporal 4B scatter ----------
__global__ void k_fill(const int* __restrict__ row, const int* __restrict__ col,
                       int* __restrict__ cursor, int* __restrict__ ccol, int E) {
  int e = blockIdx.x * blockDim.x + threadIdx.x;
  if (e >= E) return;
  int r = row[e];
  int idx = atomicAdd(&cursor[r], 1);
  __builtin_nontemporal_store(col[e], &ccol[idx]);
}

// ---------- prop v5: row-per-wave persistent, coalesced index load + shfl ----
// Gather source zbf is PRE-SCALED: zbf[c] = bf16(dis[c] * z[c]).
// (P z)[n] = -dis[n] * sum_c zbf[c]
// MODE 1: outbf[n] = bf16( dis[n] * (inA[n] - 2*dis[n]*acc) )   (scaled V)
// MODE 2: outC[n]  = inA[n] - dis[n]*acc  (+ fused BN stats)    (inA = Y0-Y2)
template <int MODE>
__global__ __launch_bounds__(256) void k_prop5(const int* __restrict__ rowptr,
                                               const int* __restrict__ ccol,
                                               const float* __restrict__ dis,
                                               const unsigned short* __restrict__ zbf,
                                               const float* __restrict__ inA,
                                               unsigned short* __restrict__ outbf,
                                               float* __restrict__ outC,
                                               float* __restrict__ sums,
                                               float* __restrict__ sumsq,
                                               int N, int nwaves) {
  int gw = blockIdx.x * 4 + (threadIdx.x >> 6);
  int lane = threadIdx.x & 63;
  int wid = threadIdx.x >> 6;
  float s = 0.f, s2 = 0.f;
  for (int n = gw; n < N; n += nwaves) {
    int beg = rowptr[n], end = rowptr[n + 1];
    float acc = 0.f;
    for (int j = beg; j < end; j += 20) {
      int myc = ccol[j + lane];  // coalesced 256B; allocation padded by 64
      float vv[20];
#pragma unroll
      for (int u = 0; u < 20; ++u) {
        int c = __shfl(myc, u, 64);
        int cc = (j + u < end) ? c : N;  // row N zeroed
        vv[u] = bf2f(zbf[(size_t)cc * 64 + lane]);
      }
#pragma unroll
      for (int u = 0; u < 20; ++u) acc += vv[u];
    }
    float dn = dis[n];
    size_t o = (size_t)n * 64 + lane;
    if (MODE == 1) {
      float V = inA[o] - 2.f * dn * acc;
      outbf[o] = f2bf(dn * V);
    } else {
      float v = inA[o] - dn * acc;
      outC[o] = v;
      s += v;
      s2 = fmaf(v, v, s2);
    }
  }
  if (MODE == 2) {
    __shared__ float red[2][4][64];
    red[0][wid][lane] = s;
    red[1][wid][lane] = s2;
    __syncthreads();
    if (wid == 0) {
      float a = red[0][0][lane] + red[0][1][lane] + red[0][2][lane] + red[0][3][lane];
      float b = red[1][0][lane] + red[1][1][lane] + red[1][2][lane] + red[1][3][lane];
      atomicAdd(&sums[lane], a);
      atomicAdd(&sumsq[lane], b);
    }
  }
}

// ---------- fused layer GEMM: A02 = X@(W0)+b - X@W2, Y1 = X@W1,
//            Y2bf = bf16(dis*X@W2). BNIN applies bn+lrelu while staging. ------
template <bool BNIN>
__global__ __launch_bounds__(512) void k_gemm192(const float* __restrict__ X,
                                                 const float* __restrict__ scale,
                                                 const float* __restrict__ shift,
                                                 const float* __restrict__ W,
                                                 const float* __restrict__ bias,
                                                 const float* __restrict__ dis,
                                                 float* __restrict__ A02,
                                                 float* __restrict__ Y1,
                                                 unsigned short* __restrict__ Y2bf,
                                                 int N) {
  __shared__ float w_s[64 * 192];   // w_s[d*192 + k*64 + h]
  __shared__ float x_s[128 * 64];
  for (int i4 = threadIdx.x; i4 < 3072; i4 += 512) {
    int k = i4 >> 10, rem = i4 & 1023;
    int d = rem >> 4, h4 = rem & 15;
    float4 v = ((const float4*)W)[i4];
    *(float4*)&w_s[d * 192 + k * 64 + h4 * 4] = v;
  }
  int rowbase = blockIdx.x * 128;
  for (int i4 = threadIdx.x; i4 < 2048; i4 += 512) {
    int r = i4 >> 4, c4 = i4 & 15;
    int row = rowbase + r;
    float4 v = (row < N) ? ((const float4*)(X + (size_t)row * 64))[c4]
                         : make_float4(0.f, 0.f, 0.f, 0.f);
    if (BNIN) {
      float4 sc = ((const float4*)scale)[c4];
      float4 sh = ((const float4*)shift)[c4];
      float a = v.x * sc.x + sh.x, b = v.y * sc.y + sh.y;
      float c = v.z * sc.z + sh.z, d = v.w * sc.w + sh.w;
      v.x = (a > 0.f) ? a : 0.01f * a;
      v.y = (b > 0.f) ? b : 0.01f * b;
      v.z = (c > 0.f) ? c : 0.01f * c;
      v.w = (d > 0.f) ? d : 0.01f * d;
    }
    *(float4*)&x_s[r * 64 + c4 * 4] = v;
  }
  __syncthreads();

  int lane = threadIdx.x & 63;
  int wid = threadIdx.x >> 6;
  int r0 = wid * 16;
  float bv = bias[lane];
  float acc[48];
#pragma unroll
  for (int r = 0; r < 16; ++r) {
    acc[r * 3 + 0] = bv;
    acc[r * 3 + 1] = 0.f;
    acc[r * 3 + 2] = 0.f;
  }

  for (int d4 = 0; d4 < 16; ++d4) {
    float w[12];
#pragma unroll
    for (int k = 0; k < 4; ++k)
#pragma unroll
      for (int j = 0; j < 3; ++j)
        w[k * 3 + j] = w_s[(d4 * 4 + k) * 192 + j * 64 + lane];
#pragma unroll
    for (int r = 0; r < 16; ++r) {
      float4 xv = *(const float4*)&x_s[(r0 + r) * 64 + d4 * 4];  // bcast
#pragma unroll
      for (int j = 0; j < 3; ++j) {
        float a = acc[r * 3 + j];
        a = fmaf(xv.x, w[0 * 3 + j], a);
        a = fmaf(xv.y, w[1 * 3 + j], a);
        a = fmaf(xv.z, w[2 * 3 + j], a);
        a = fmaf(xv.w, w[3 * 3 + j], a);
        acc[r * 3 + j] = a;
      }
    }
  }

#pragma unroll
  for (int r = 0; r < 16; ++r) {
    int row = rowbase + r0 + r;
    if (row < N) {
      size_t o = (size_t)row * 64 + lane;
      A02[o] = acc[r * 3 + 0] - acc[r * 3 + 2];
      Y1[o] = acc[r * 3 + 1];
      Y2bf[o] = f2bf(dis[row] * acc[r * 3 + 2]);
    }
  }
}

// ---------- shortcut GEMM: S = x @ W_sc + b_sc ----------
__global__ __launch_bounds__(512) void k_gemmsc(const float* __restrict__ X,
                                                const float* __restrict__ W,
                                                const float* __restrict__ bias,
                                                float* __restrict__ S, int N) {
  __shared__ float w_s[64 * 64];
  __shared__ float x_s[128 * 64];
  for (int i4 = threadIdx.x; i4 < 1024; i4 += 512)
    *(float4*)&w_s[i4 * 4] = ((const float4*)W)[i4];
  int rowbase = blockIdx.x * 128;
  for (int i4 = threadIdx.x; i4 < 2048; i4 += 512) {
    int r = i4 >> 4, c4 = i4 & 15;
    int row = rowbase + r;
    float4 v = (row < N) ? ((const float4*)(X + (size_t)row * 64))[c4]
                         : make_float4(0.f, 0.f, 0.f, 0.f);
    *(float4*)&x_s[r * 64 + c4 * 4] = v;
  }
  __syncthreads();

  int lane = threadIdx.x & 63;
  int wid = threadIdx.x >> 6;
  int r0 = wid * 16;
  float bv = bias[lane];
  float acc[16];
#pragma unroll
  for (int r = 0; r < 16; ++r) acc[r] = bv;

  for (int d4 = 0; d4 < 16; ++d4) {
    float w0 = w_s[(d4 * 4 + 0) * 64 + lane];
    float w1 = w_s[(d4 * 4 + 1) * 64 + lane];
    float w2 = w_s[(d4 * 4 + 2) * 64 + lane];
    float w3 = w_s[(d4 * 4 + 3) * 64 + lane];
#pragma unroll
    for (int r = 0; r < 16; ++r) {
      float4 xv = *(const float4*)&x_s[(r0 + r) * 64 + d4 * 4];
      float a = acc[r];
      a = fmaf(xv.x, w0, a);
      a = fmaf(xv.y, w1, a);
      a = fmaf(xv.z, w2, a);
      a = fmaf(xv.w, w3, a);
      acc[r] = a;
    }
  }

#pragma unroll
  for (int r = 0; r < 16; ++r) {
    int row = rowbase + r0 + r;
    if (row < N) S[(size_t)row * 64 + lane] = acc[r];
  }
}

__global__ void k_bncoef(const float* __restrict__ sums, const float* __restrict__ sumsq,
                         const float* __restrict__ g, const float* __restrict__ be,
                         float* __restrict__ scale, float* __restrict__ shift, int N) {
  int h = threadIdx.x;
  if (h >= 64) return;
  float inv_n = 1.0f / (float)N;
  float mu = sums[h] * inv_n;
  float var = sumsq[h] * inv_n - mu * mu;
  float sc = g[h] * rsqrtf(var + 1e-5f);
  scale[h] = sc;
  shift[h] = be[h] - mu * sc;
}

// ---------- pooling ----------
__global__ void k_poolinit(unsigned* __restrict__ pooled, int n) {
  int i = blockIdx.x * blockDim.x + threadIdx.x;
  if (i < n) pooled[i] = 0x007FFFFFu;  // key(-inf)
}

// fused: h = lrelu(bn(C)) + S; segment-max into pooled
__global__ void k_bnpool(const float* __restrict__ C, const float* __restrict__ scale,
                         const float* __restrict__ shift, const float* __restrict__ S,
                         const int* __restrict__ batch, unsigned* __restrict__ pooled,
                         int N) {
  int t = threadIdx.x;
  int h = t & 63;
  int rsub = t >> 6;
  int base = blockIdx.x * 64;
  float sc = scale[h], sh = shift[h];
  int cur_g = -1;
  unsigned best = 0;
  for (int i = 0; i < 16; ++i) {
    int n = base + rsub + 4 * i;
    if (n >= N) break;
    int g = batch[n];
    size_t o = (size_t)n * 64 + h;
    float a = C[o] * sc + sh;
    a = (a > 0.f) ? a : 0.01f * a;
    a += S[o];
    unsigned k = f2key(a);
    if (g != cur_g) {
      if (cur_g >= 0) atomicMax(&pooled[cur_g * 64 + h], best);
      cur_g = g;
      best = k;
    } else {
      best = max(best, k);
    }
  }
  if (cur_g >= 0) atomicMax(&pooled[cur_g * 64 + h], best);
}

__global__ void k_final(const unsigned* __restrict__ pooled, const float* __restrict__ w_lin,
                        const float* __restrict__ b_lin, float* __restrict__ out) {
  int g = blockIdx.x;
  int h = threadIdx.x;
  float v = key2f(pooled[g * 64 + h]) * w_lin[h];
  for (int off = 32; off > 0; off >>= 1) v += __shfl_down(v, off, 64);
  if (h == 0) out[g] = v + b_lin[0];
}

extern "C" void kernel_launch(void* const* d_in, const int* in_sizes, int n_in,
                              void* d_out, int out_size, void* d_ws, size_t ws_size,
                              hipStream_t stream) {
  const float* x = (const float*)d_in[0];
  const int* ei = (const int*)d_in[1];
  const int* batch = (const int*)d_in[2];
  const float* w1 = (const float*)d_in[3];
  const float* b1 = (const float*)d_in[4];
  const float* w2 = (const float*)d_in[5];
  const float* b2 = (const float*)d_in[6];
  const float* w3 = (const float*)d_in[7];
  const float* b3 = (const float*)d_in[8];
  const float* g1 = (const float*)d_in[9];
  const float* be1 = (const float*)d_in[10];
  const float* g2 = (const float*)d_in[11];
  const float* be2 = (const float*)d_in[12];
  const float* g3 = (const float*)d_in[13];
  const float* be3 = (const float*)d_in[14];
  const float* w_sc = (const float*)d_in[15];
  const float* b_sc = (const float*)d_in[16];
  const float* w_lin = (const float*)d_in[17];
  const float* b_lin = (const float*)d_in[18];

  int N = in_sizes[0] / 64;
  int E = in_sizes[1] / 2;
  int G = out_size;
  const int* row = ei;
  const int* col = ei + E;

  char* p = (char*)d_ws;
  auto carve = [&](size_t bytes) -> void* {
    void* r = (void*)p;
    p += (bytes + 255) & ~(size_t)255;
    return r;
  };
  int* cnt = (int*)carve((size_t)N * 4);
  float* dis = (float*)carve((size_t)N * 4);
  int* rowptr = (int*)carve((size_t)(N + 1) * 4);
  int* cursor = (int*)carve((size_t)N * 4);
  int* incl = (int*)carve((size_t)N * 4);
  int* bsum = (int*)carve(1024);
  int* bex = (int*)carve(1024);
  int* ccol = (int*)carve((size_t)(E + 64) * 4);   // +64 pad for coalesced over-read
  float* A02 = (float*)carve((size_t)N * 64 * 4);
  float* Y1 = (float*)carve((size_t)N * 64 * 4);
  float* C = (float*)carve((size_t)N * 64 * 4);
  float* S = (float*)carve((size_t)N * 64 * 4);
  unsigned short* Y2bf = (unsigned short*)carve((size_t)(N + 1) * 64 * 2);  // row N = 0
  unsigned short* Vbf = (unsigned short*)carve((size_t)(N + 1) * 64 * 2);   // row N = 0
  float* stats = (float*)carve(256 * 4);  // sums|sumsq|scale|shift
  unsigned* pooled = (unsigned*)carve((size_t)G * 64 * 4);

  // ---- graph structure ----
  k_zero<<<DIV_UP(N, 256), 256, 0, stream>>>(cnt, N);
  k_count<<<DIV_UP(E, 256), 256, 0, stream>>>(row, cnt, E);
  k_dis<<<DIV_UP(N, 256), 256, 0, stream>>>(cnt, dis, N);
  int nb = DIV_UP(N, 1024);
  k_scan1<<<nb, 1024, 0, stream>>>(cnt, incl, bsum, N);
  k_scan2<<<1, 64, 0, stream>>>(bsum, bex, nb);
  k_scan3<<<DIV_UP(N, 256), 256, 0, stream>>>(incl, cnt, bex, rowptr, cursor, N, E);
  k_fill<<<DIV_UP(E, 256), 256, 0, stream>>>(row, col, cursor, ccol, E);

  // zero the sentinel rows (row N) of the bf16 gather arrays
  k_zero<<<1, 64, 0, stream>>>((int*)(Y2bf + (size_t)N * 64), 32);
  k_zero<<<1, 64, 0, stream>>>((int*)(Vbf + (size_t)N * 64), 32);

  // shortcut (independent): S = x @ w_sc + b_sc
  int NBG = DIV_UP(N, 128);
  k_gemmsc<<<NBG, 512, 0, stream>>>(x, w_sc, b_sc, S, N);

  const float* Ws[3] = {w1, w2, w3};
  const float* bs[3] = {b1, b2, b3};
  const float* gs[3] = {g1, g2, g3};
  const float* bes[3] = {be1, be2, be3};

  const int PBLK = 2048;      // persistent blocks, 4 waves each
  const int NWAVE = PBLK * 4;
  for (int l = 0; l < 3; ++l) {
    if (l == 0)
      k_gemm192<false><<<NBG, 512, 0, stream>>>(x, nullptr, nullptr, Ws[l], bs[l], dis,
                                                A02, Y1, Y2bf, N);
    else
      k_gemm192<true><<<NBG, 512, 0, stream>>>(C, stats + 128, stats + 192, Ws[l], bs[l],
                                               dis, A02, Y1, Y2bf, N);
    k_zero<<<1, 256, 0, stream>>>((int*)stats, 128);
    // Vbf = bf16( dis * (Y1 + 2*P*Y2) )
    k_prop5<1><<<PBLK, 256, 0, stream>>>(rowptr, ccol, dis, Y2bf, Y1,
                                         Vbf, nullptr, nullptr, nullptr, N, NWAVE);
    // C = (Y0 - Y2) + P*V  (+ fused BN stats)
    k_prop5<2><<<PBLK, 256, 0, stream>>>(rowptr, ccol, dis, Vbf, A02,
                                         nullptr, C, stats, stats + 64, N, NWAVE);
    k_bncoef<<<1, 64, 0, stream>>>(stats, stats + 64, gs[l], bes[l],
                                   stats + 128, stats + 192, N);
  }

  k_poolinit<<<DIV_UP(G * 64, 256), 256, 0, stream>>>(pooled, G * 64);
  k_bnpool<<<DIV_UP(N, 64), 256, 0, stream>>>(C, stats + 128, stats + 192, S, batch,
                                              pooled, N);
  k_final<<<G, 64, 0, stream>>>(pooled, w_lin, b_lin, (float*)d_out);
}

// Round 11
// 930.346 us; speedup vs baseline: 1.2017x; 1.2017x over previous
//
#include <hip/hip_runtime.h>

#define DIV_UP(a,b) (((a)+(b)-1)/(b))

// ---------- ordered-uint float max keys ----------
__device__ __forceinline__ unsigned f2key(float f) {
  unsigned u = __float_as_uint(f);
  return (u & 0x80000000u) ? ~u : (u | 0x80000000u);
}
__device__ __forceinline__ float key2f(unsigned u) {
  unsigned b = (u & 0x80000000u) ? (u ^ 0x80000000u) : ~u;
  return __uint_as_float(b);
}

// ---------- bf16 pack/unpack (RNE) ----------
__device__ __forceinline__ unsigned short f2bf(float f) {
  unsigned u = __float_as_uint(f);
  unsigned r = u + 0x7FFFu + ((u >> 16) & 1u);
  return (unsigned short)(r >> 16);
}
__device__ __forceinline__ float bf2f(unsigned short s) {
  return __uint_as_float(((unsigned)s) << 16);
}

// ---------- utility ----------
__global__ void k_zero(int* p, int n) {
  int i = blockIdx.x * blockDim.x + threadIdx.x;
  if (i < n) p[i] = 0;
}

// ---------- degree count ----------
__global__ void k_count(const int* __restrict__ row, int* __restrict__ cnt, int E) {
  int e = blockIdx.x * blockDim.x + threadIdx.x;
  if (e < E) atomicAdd(&cnt[row[e]], 1);
}

__global__ void k_dis(const int* __restrict__ cnt, float* __restrict__ dis, int N) {
  int i = blockIdx.x * blockDim.x + threadIdx.x;
  if (i < N) {
    int c = cnt[i];
    dis[i] = (c > 0) ? rsqrtf((float)c) : 0.0f;
  }
}

// ---------- 3-kernel exclusive scan over cnt -> rowptr ----------
__global__ void k_scan1(const int* __restrict__ cnt, int* __restrict__ incl,
                        int* __restrict__ bsum, int N) {
  __shared__ int s[1024];
  int t = threadIdx.x;
  int i = blockIdx.x * 1024 + t;
  int v = (i < N) ? cnt[i] : 0;
  s[t] = v;
  __syncthreads();
  for (int off = 1; off < 1024; off <<= 1) {
    int add = (t >= off) ? s[t - off] : 0;
    __syncthreads();
    s[t] += add;
    __syncthreads();
  }
  if (i < N) incl[i] = s[t];
  if (t == 1023) bsum[blockIdx.x] = s[1023];
}

__global__ void k_scan2(const int* __restrict__ bsum, int* __restrict__ bex, int nb) {
  if (threadIdx.x == 0) {
    int run = 0;
    for (int b = 0; b < nb; ++b) { bex[b] = run; run += bsum[b]; }
  }
}

__global__ void k_scan3(const int* __restrict__ incl, const int* __restrict__ cnt,
                        const int* __restrict__ bex, int* __restrict__ rowptr,
                        int* __restrict__ cursor, int N, int E) {
  int i = blockIdx.x * blockDim.x + threadIdx.x;
  if (i < N) {
    int v = incl[i] - cnt[i] + bex[i >> 10];
    rowptr[i] = v;
    cursor[i] = v;
  }
  if (i == 0) rowptr[N] = E;
}

// ---------- CSR fill: col only, non-temporal 4B scatter ----------
__global__ void k_fill(const int* __restrict__ row, const int* __restrict__ col,
                       int* __restrict__ cursor, int* __restrict__ ccol, int E) {
  int e = blockIdx.x * blockDim.x + threadIdx.x;
  if (e >= E) return;
  int r = row[e];
  int idx = atomicAdd(&cursor[r], 1);
  __builtin_nontemporal_store(col[e], &ccol[idx]);
}

// ---------- prop v4 (R9 structure): row-per-wave persistent, 16-deep --------
// Gather source zbf is PRE-SCALED: zbf[c] = bf16(dis[c] * z[c]).
// (P z)[n] = -dis[n] * sum_c zbf[c]
// MODE 1: outbf[n] = bf16( dis[n] * (inA[n] - 2*dis[n]*acc) )   (scaled V)
// MODE 2: outC[n]  = inA[n] - dis[n]*acc  (+ fused BN stats)    (inA = Y0-Y2)
template <int MODE>
__global__ __launch_bounds__(256) void k_prop4(const int* __restrict__ rowptr,
                                               const int* __restrict__ ccol,
                                               const float* __restrict__ dis,
                                               const unsigned short* __restrict__ zbf,
                                               const float* __restrict__ inA,
                                               unsigned short* __restrict__ outbf,
                                               float* __restrict__ outC,
                                               float* __restrict__ sums,
                                               float* __restrict__ sumsq,
                                               int N, int nwaves) {
  int gw = blockIdx.x * 4 + (threadIdx.x >> 6);
  int lane = threadIdx.x & 63;
  int wid = threadIdx.x >> 6;
  float s = 0.f, s2 = 0.f;
  for (int n = gw; n < N; n += nwaves) {
    int beg = rowptr[n], end = rowptr[n + 1];
    float acc = 0.f;
    for (int j = beg; j < end; j += 16) {
      int cc[16];
#pragma unroll
      for (int u = 0; u < 16; ++u) {
        int jj = j + u;
        int c = ccol[jj];            // allocation padded by 16 -> safe load
        cc[u] = (jj < end) ? c : N;  // row N is zeroed
      }
      float vv[16];
#pragma unroll
      for (int u = 0; u < 16; ++u) vv[u] = bf2f(zbf[(size_t)cc[u] * 64 + lane]);
#pragma unroll
      for (int u = 0; u < 16; ++u) acc += vv[u];
    }
    float dn = dis[n];
    size_t o = (size_t)n * 64 + lane;
    if (MODE == 1) {
      float V = inA[o] - 2.f * dn * acc;
      outbf[o] = f2bf(dn * V);
    } else {
      float v = inA[o] - dn * acc;
      outC[o] = v;
      s += v;
      s2 = fmaf(v, v, s2);
    }
  }
  if (MODE == 2) {
    __shared__ float red[2][4][64];
    red[0][wid][lane] = s;
    red[1][wid][lane] = s2;
    __syncthreads();
    if (wid == 0) {
      float a = red[0][0][lane] + red[0][1][lane] + red[0][2][lane] + red[0][3][lane];
      float b = red[1][0][lane] + red[1][1][lane] + red[1][2][lane] + red[1][3][lane];
      atomicAdd(&sums[lane], a);
      atomicAdd(&sumsq[lane], b);
    }
  }
}

// ---------- fused layer GEMM: A02 = X@W0+b - X@W2, Y1 = X@W1,
//            Y2bf = bf16(dis*X@W2). BNIN applies bn+lrelu while staging. ------
template <bool BNIN>
__global__ __launch_bounds__(512) void k_gemm192(const float* __restrict__ X,
                                                 const float* __restrict__ scale,
                                                 const float* __restrict__ shift,
                                                 const float* __restrict__ W,
                                                 const float* __restrict__ bias,
                                                 const float* __restrict__ dis,
                                                 float* __restrict__ A02,
                                                 float* __restrict__ Y1,
                                                 unsigned short* __restrict__ Y2bf,
                                                 int N) {
  __shared__ float w_s[64 * 192];   // w_s[d*192 + k*64 + h]
  __shared__ float x_s[128 * 64];
  for (int i4 = threadIdx.x; i4 < 3072; i4 += 512) {
    int k = i4 >> 10, rem = i4 & 1023;
    int d = rem >> 4, h4 = rem & 15;
    float4 v = ((const float4*)W)[i4];
    *(float4*)&w_s[d * 192 + k * 64 + h4 * 4] = v;
  }
  int rowbase = blockIdx.x * 128;
  for (int i4 = threadIdx.x; i4 < 2048; i4 += 512) {
    int r = i4 >> 4, c4 = i4 & 15;
    int row = rowbase + r;
    float4 v = (row < N) ? ((const float4*)(X + (size_t)row * 64))[c4]
                         : make_float4(0.f, 0.f, 0.f, 0.f);
    if (BNIN) {
      float4 sc = ((const float4*)scale)[c4];
      float4 sh = ((const float4*)shift)[c4];
      float a = v.x * sc.x + sh.x, b = v.y * sc.y + sh.y;
      float c = v.z * sc.z + sh.z, d = v.w * sc.w + sh.w;
      v.x = (a > 0.f) ? a : 0.01f * a;
      v.y = (b > 0.f) ? b : 0.01f * b;
      v.z = (c > 0.f) ? c : 0.01f * c;
      v.w = (d > 0.f) ? d : 0.01f * d;
    }
    *(float4*)&x_s[r * 64 + c4 * 4] = v;
  }
  __syncthreads();

  int lane = threadIdx.x & 63;
  int wid = threadIdx.x >> 6;
  int r0 = wid * 16;
  float bv = bias[lane];
  float acc[48];
#pragma unroll
  for (int r = 0; r < 16; ++r) {
    acc[r * 3 + 0] = bv;
    acc[r * 3 + 1] = 0.f;
    acc[r * 3 + 2] = 0.f;
  }

  for (int d4 = 0; d4 < 16; ++d4) {
    float w[12];
#pragma unroll
    for (int k = 0; k < 4; ++k)
#pragma unroll
      for (int j = 0; j < 3; ++j)
        w[k * 3 + j] = w_s[(d4 * 4 + k) * 192 + j * 64 + lane];
#pragma unroll
    for (int r = 0; r < 16; ++r) {
      float4 xv = *(const float4*)&x_s[(r0 + r) * 64 + d4 * 4];  // bcast
#pragma unroll
      for (int j = 0; j < 3; ++j) {
        float a = acc[r * 3 + j];
        a = fmaf(xv.x, w[0 * 3 + j], a);
        a = fmaf(xv.y, w[1 * 3 + j], a);
        a = fmaf(xv.z, w[2 * 3 + j], a);
        a = fmaf(xv.w, w[3 * 3 + j], a);
        acc[r * 3 + j] = a;
      }
    }
  }

#pragma unroll
  for (int r = 0; r < 16; ++r) {
    int row = rowbase + r0 + r;
    if (row < N) {
      size_t o = (size_t)row * 64 + lane;
      A02[o] = acc[r * 3 + 0] - acc[r * 3 + 2];
      Y1[o] = acc[r * 3 + 1];
      Y2bf[o] = f2bf(dis[row] * acc[r * 3 + 2]);
    }
  }
}

// ---------- shortcut GEMM: S = x @ W_sc + b_sc ----------
__global__ __launch_bounds__(512) void k_gemmsc(const float* __restrict__ X,
                                                const float* __restrict__ W,
                                                const float* __restrict__ bias,
                                                float* __restrict__ S, int N) {
  __shared__ float w_s[64 * 64];
  __shared__ float x_s[128 * 64];
  for (int i4 = threadIdx.x; i4 < 1024; i4 += 512)
    *(float4*)&w_s[i4 * 4] = ((const float4*)W)[i4];
  int rowbase = blockIdx.x * 128;
  for (int i4 = threadIdx.x; i4 < 2048; i4 += 512) {
    int r = i4 >> 4, c4 = i4 & 15;
    int row = rowbase + r;
    float4 v = (row < N) ? ((const float4*)(X + (size_t)row * 64))[c4]
                         : make_float4(0.f, 0.f, 0.f, 0.f);
    *(float4*)&x_s[r * 64 + c4 * 4] = v;
  }
  __syncthreads();

  int lane = threadIdx.x & 63;
  int wid = threadIdx.x >> 6;
  int r0 = wid * 16;
  float bv = bias[lane];
  float acc[16];
#pragma unroll
  for (int r = 0; r < 16; ++r) acc[r] = bv;

  for (int d4 = 0; d4 < 16; ++d4) {
    float w0 = w_s[(d4 * 4 + 0) * 64 + lane];
    float w1 = w_s[(d4 * 4 + 1) * 64 + lane];
    float w2 = w_s[(d4 * 4 + 2) * 64 + lane];
    float w3 = w_s[(d4 * 4 + 3) * 64 + lane];
#pragma unroll
    for (int r = 0; r < 16; ++r) {
      float4 xv = *(const float4*)&x_s[(r0 + r) * 64 + d4 * 4];
      float a = acc[r];
      a = fmaf(xv.x, w0, a);
      a = fmaf(xv.y, w1, a);
      a = fmaf(xv.z, w2, a);
      a = fmaf(xv.w, w3, a);
      acc[r] = a;
    }
  }

#pragma unroll
  for (int r = 0; r < 16; ++r) {
    int row = rowbase + r0 + r;
    if (row < N) S[(size_t)row * 64 + lane] = acc[r];
  }
}

__global__ void k_bncoef(const float* __restrict__ sums, const float* __restrict__ sumsq,
                         const float* __restrict__ g, const float* __restrict__ be,
                         float* __restrict__ scale, float* __restrict__ shift, int N) {
  int h = threadIdx.x;
  if (h >= 64) return;
  float inv_n = 1.0f / (float)N;
  float mu = sums[h] * inv_n;
  float var = sumsq[h] * inv_n - mu * mu;
  float sc = g[h] * rsqrtf(var + 1e-5f);
  scale[h] = sc;
  shift[h] = be[h] - mu * sc;
}

// ---------- pooling ----------
__global__ void k_poolinit(unsigned* __restrict__ pooled, int n) {
  int i = blockIdx.x * blockDim.x + threadIdx.x;
  if (i < n) pooled[i] = 0x007FFFFFu;  // key(-inf)
}

// fused: h = lrelu(bn(C)) + S; segment-max into pooled
__global__ void k_bnpool(const float* __restrict__ C, const float* __restrict__ scale,
                         const float* __restrict__ shift, const float* __restrict__ S,
                         const int* __restrict__ batch, unsigned* __restrict__ pooled,
                         int N) {
  int t = threadIdx.x;
  int h = t & 63;
  int rsub = t >> 6;
  int base = blockIdx.x * 64;
  float sc = scale[h], sh = shift[h];
  int cur_g = -1;
  unsigned best = 0;
  for (int i = 0; i < 16; ++i) {
    int n = base + rsub + 4 * i;
    if (n >= N) break;
    int g = batch[n];
    size_t o = (size_t)n * 64 + h;
    float a = C[o] * sc + sh;
    a = (a > 0.f) ? a : 0.01f * a;
    a += S[o];
    unsigned k = f2key(a);
    if (g != cur_g) {
      if (cur_g >= 0) atomicMax(&pooled[cur_g * 64 + h], best);
      cur_g = g;
      best = k;
    } else {
      best = max(best, k);
    }
  }
  if (cur_g >= 0) atomicMax(&pooled[cur_g * 64 + h], best);
}

__global__ void k_final(const unsigned* __restrict__ pooled, const float* __restrict__ w_lin,
                        const float* __restrict__ b_lin, float* __restrict__ out) {
  int g = blockIdx.x;
  int h = threadIdx.x;
  float v = key2f(pooled[g * 64 + h]) * w_lin[h];
  for (int off = 32; off > 0; off >>= 1) v += __shfl_down(v, off, 64);
  if (h == 0) out[g] = v + b_lin[0];
}

extern "C" void kernel_launch(void* const* d_in, const int* in_sizes, int n_in,
                              void* d_out, int out_size, void* d_ws, size_t ws_size,
                              hipStream_t stream) {
  const float* x = (const float*)d_in[0];
  const int* ei = (const int*)d_in[1];
  const int* batch = (const int*)d_in[2];
  const float* w1 = (const float*)d_in[3];
  const float* b1 = (const float*)d_in[4];
  const float* w2 = (const float*)d_in[5];
  const float* b2 = (const float*)d_in[6];
  const float* w3 = (const float*)d_in[7];
  const float* b3 = (const float*)d_in[8];
  const float* g1 = (const float*)d_in[9];
  const float* be1 = (const float*)d_in[10];
  const float* g2 = (const float*)d_in[11];
  const float* be2 = (const float*)d_in[12];
  const float* g3 = (const float*)d_in[13];
  const float* be3 = (const float*)d_in[14];
  const float* w_sc = (const float*)d_in[15];
  const float* b_sc = (const float*)d_in[16];
  const float* w_lin = (const float*)d_in[17];
  const float* b_lin = (const float*)d_in[18];

  int N = in_sizes[0] / 64;
  int E = in_sizes[1] / 2;
  int G = out_size;
  const int* row = ei;
  const int* col = ei + E;

  char* p = (char*)d_ws;
  auto carve = [&](size_t bytes) -> void* {
    void* r = (void*)p;
    p += (bytes + 255) & ~(size_t)255;
    return r;
  };
  int* cnt = (int*)carve((size_t)N * 4);
  float* dis = (float*)carve((size_t)N * 4);
  int* rowptr = (int*)carve((size_t)(N + 1) * 4);
  int* cursor = (int*)carve((size_t)N * 4);
  int* incl = (int*)carve((size_t)N * 4);
  int* bsum = (int*)carve(1024);
  int* bex = (int*)carve(1024);
  int* ccol = (int*)carve((size_t)(E + 64) * 4);   // +64 pad for batch over-read
  float* A02 = (float*)carve((size_t)N * 64 * 4);
  float* Y1 = (float*)carve((size_t)N * 64 * 4);
  float* C = (float*)carve((size_t)N * 64 * 4);
  float* S = (float*)carve((size_t)N * 64 * 4);
  unsigned short* Y2bf = (unsigned short*)carve((size_t)(N + 1) * 64 * 2);  // row N = 0
  unsigned short* Vbf = (unsigned short*)carve((size_t)(N + 1) * 64 * 2);   // row N = 0
  float* stats = (float*)carve(256 * 4);  // sums|sumsq|scale|shift
  unsigned* pooled = (unsigned*)carve((size_t)G * 64 * 4);

  // ---- graph structure ----
  k_zero<<<DIV_UP(N, 256), 256, 0, stream>>>(cnt, N);
  k_count<<<DIV_UP(E, 256), 256, 0, stream>>>(row, cnt, E);
  k_dis<<<DIV_UP(N, 256), 256, 0, stream>>>(cnt, dis, N);
  int nb = DIV_UP(N, 1024);
  k_scan1<<<nb, 1024, 0, stream>>>(cnt, incl, bsum, N);
  k_scan2<<<1, 64, 0, stream>>>(bsum, bex, nb);
  k_scan3<<<DIV_UP(N, 256), 256, 0, stream>>>(incl, cnt, bex, rowptr, cursor, N, E);
  k_fill<<<DIV_UP(E, 256), 256, 0, stream>>>(row, col, cursor, ccol, E);

  // zero the sentinel rows (row N) of the bf16 gather arrays
  k_zero<<<1, 64, 0, stream>>>((int*)(Y2bf + (size_t)N * 64), 32);
  k_zero<<<1, 64, 0, stream>>>((int*)(Vbf + (size_t)N * 64), 32);

  // shortcut (independent): S = x @ w_sc + b_sc
  int NBG = DIV_UP(N, 128);
  k_gemmsc<<<NBG, 512, 0, stream>>>(x, w_sc, b_sc, S, N);

  const float* Ws[3] = {w1, w2, w3};
  const float* bs[3] = {b1, b2, b3};
  const float* gs[3] = {g1, g2, g3};
  const float* bes[3] = {be1, be2, be3};

  const int PBLK = 2048;      // persistent blocks, 4 waves each
  const int NWAVE = PBLK * 4;
  for (int l = 0; l < 3; ++l) {
    if (l == 0)
      k_gemm192<false><<<NBG, 512, 0, stream>>>(x, nullptr, nullptr, Ws[l], bs[l], dis,
                                                A02, Y1, Y2bf, N);
    else
      k_gemm192<true><<<NBG, 512, 0, stream>>>(C, stats + 128, stats + 192, Ws[l], bs[l],
                                               dis, A02, Y1, Y2bf, N);
    k_zero<<<1, 256, 0, stream>>>((int*)stats, 128);
    // Vbf = bf16( dis * (Y1 + 2*P*Y2) )
    k_prop4<1><<<PBLK, 256, 0, stream>>>(rowptr, ccol, dis, Y2bf, Y1,
                                         Vbf, nullptr, nullptr, nullptr, N, NWAVE);
    // C = (Y0 - Y2) + P*V  (+ fused BN stats)
    k_prop4<2><<<PBLK, 256, 0, stream>>>(rowptr, ccol, dis, Vbf, A02,
                                         nullptr, C, stats, stats + 64, N, NWAVE);
    k_bncoef<<<1, 64, 0, stream>>>(stats, stats + 64, gs[l], bes[l],
                                   stats + 128, stats + 192, N);
  }

  k_poolinit<<<DIV_UP(G * 64, 256), 256, 0, stream>>>(pooled, G * 64);
  k_bnpool<<<DIV_UP(N, 64), 256, 0, stream>>>(C, stats + 128, stats + 192, S, batch,
                                              pooled, N);
  k_final<<<G, 64, 0, stream>>>(pooled, w_lin, b_lin, (float*)d_out);
}

// Round 12
// 910.301 us; speedup vs baseline: 1.2281x; 1.0220x over previous
//
#include <hip/hip_runtime.h>

#define DIV_UP(a,b) (((a)+(b)-1)/(b))

typedef float v4f __attribute__((ext_vector_type(4)));

// ---------- non-temporal helpers ----------
__device__ __forceinline__ float4 ntload4(const float* p) {
  v4f v = __builtin_nontemporal_load((const v4f*)p);
  return make_float4(v.x, v.y, v.z, v.w);
}
__device__ __forceinline__ void ntstore4(float* p, float4 f) {
  v4f v = {f.x, f.y, f.z, f.w};
  __builtin_nontemporal_store(v, (v4f*)p);
}

// ---------- ordered-uint float max keys ----------
__device__ __forceinline__ unsigned f2key(float f) {
  unsigned u = __float_as_uint(f);
  return (u & 0x80000000u) ? ~u : (u | 0x80000000u);
}
__device__ __forceinline__ float key2f(unsigned u) {
  unsigned b = (u & 0x80000000u) ? (u ^ 0x80000000u) : ~u;
  return __uint_as_float(b);
}

// ---------- bf16 pack/unpack (RNE) ----------
__device__ __forceinline__ unsigned short f2bf(float f) {
  unsigned u = __float_as_uint(f);
  unsigned r = u + 0x7FFFu + ((u >> 16) & 1u);
  return (unsigned short)(r >> 16);
}
__device__ __forceinline__ float bf2f(unsigned short s) {
  return __uint_as_float(((unsigned)s) << 16);
}

// ---------- utility ----------
__global__ void k_zero(int* p, int n) {
  int i = blockIdx.x * blockDim.x + threadIdx.x;
  if (i < n) p[i] = 0;
}

__global__ void k_dis(const int* __restrict__ cnt, float* __restrict__ dis, int N) {
  int i = blockIdx.x * blockDim.x + threadIdx.x;
  if (i < N) {
    int c = cnt[i];
    dis[i] = (c > 0) ? rsqrtf((float)c) : 0.0f;
  }
}

// ---------- 3-kernel exclusive scan over cnt -> rowptr ----------
__global__ void k_scan1(const int* __restrict__ cnt, int* __restrict__ incl,
                        int* __restrict__ bsum, int N) {
  __shared__ int s[1024];
  int t = threadIdx.x;
  int i = blockIdx.x * 1024 + t;
  int v = (i < N) ? cnt[i] : 0;
  s[t] = v;
  __syncthreads();
  for (int off = 1; off < 1024; off <<= 1) {
    int add = (t >= off) ? s[t - off] : 0;
    __syncthreads();
    s[t] += add;
    __syncthreads();
  }
  if (i < N) incl[i] = s[t];
  if (t == 1023) bsum[blockIdx.x] = s[1023];
}

__global__ void k_scan2(const int* __restrict__ bsum, int* __restrict__ bex, int nb) {
  if (threadIdx.x == 0) {
    int run = 0;
    for (int b = 0; b < nb; ++b) { bex[b] = run; run += bsum[b]; }
  }
}

__global__ void k_scan3(const int* __restrict__ incl, const int* __restrict__ cnt,
                        const int* __restrict__ bex, int* __restrict__ rowptr,
                        int* __restrict__ cursor, int N, int E) {
  int i = blockIdx.x * blockDim.x + threadIdx.x;
  if (i < N) {
    int v = incl[i] - cnt[i] + bex[i >> 10];
    rowptr[i] = v;
    cursor[i] = v;
  }
  if (i == 0) rowptr[N] = E;
}

// ---------- shortcut GEMM body: S = x @ W_sc + b_sc ----------
__device__ __forceinline__ void gemmsc_body(float* w_s, float* x_s, int bid,
                                            const float* __restrict__ X,
                                            const float* __restrict__ W,
                                            const float* __restrict__ bias,
                                            float* __restrict__ S, int N) {
  for (int i4 = threadIdx.x; i4 < 1024; i4 += 512)
    *(float4*)&w_s[i4 * 4] = ((const float4*)W)[i4];
  int rowbase = bid * 128;
  for (int i4 = threadIdx.x; i4 < 2048; i4 += 512) {
    int r = i4 >> 4, c4 = i4 & 15;
    int row = rowbase + r;
    float4 v = (row < N) ? ntload4(X + (size_t)row * 64 + c4 * 4)
                         : make_float4(0.f, 0.f, 0.f, 0.f);
    *(float4*)&x_s[r * 64 + c4 * 4] = v;
  }
  __syncthreads();

  int lane = threadIdx.x & 63;
  int wid = threadIdx.x >> 6;
  int r0 = wid * 16;
  float bv = bias[lane];
  float acc[16];
#pragma unroll
  for (int r = 0; r < 16; ++r) acc[r] = bv;

  for (int d4 = 0; d4 < 16; ++d4) {
    float w0 = w_s[(d4 * 4 + 0) * 64 + lane];
    float w1 = w_s[(d4 * 4 + 1) * 64 + lane];
    float w2 = w_s[(d4 * 4 + 2) * 64 + lane];
    float w3 = w_s[(d4 * 4 + 3) * 64 + lane];
#pragma unroll
    for (int r = 0; r < 16; ++r) {
      float4 xv = *(const float4*)&x_s[(r0 + r) * 64 + d4 * 4];
      float a = acc[r];
      a = fmaf(xv.x, w0, a);
      a = fmaf(xv.y, w1, a);
      a = fmaf(xv.z, w2, a);
      a = fmaf(xv.w, w3, a);
      acc[r] = a;
    }
  }

#pragma unroll
  for (int r = 0; r < 16; ++r) {
    int row = rowbase + r0 + r;
    if (row < N) __builtin_nontemporal_store(acc[r], &S[(size_t)row * 64 + lane]);
  }
}

// ---------- fused layer GEMM body ----------
// A02bf = bf16(X@W0+b - X@W2), Y1bf = bf16(X@W1), Y2bf = bf16(dis*X@W2)
template <bool BNIN>
__device__ __forceinline__ void gemm192_body(float* w_s, float* x_s, int bid,
                                             const float* __restrict__ X,
                                             const float* __restrict__ scale,
                                             const float* __restrict__ shift,
                                             const float* __restrict__ W,
                                             const float* __restrict__ bias,
                                             const float* __restrict__ dis,
                                             unsigned short* __restrict__ A02bf,
                                             unsigned short* __restrict__ Y1bf,
                                             unsigned short* __restrict__ Y2bf,
                                             int N) {
  for (int i4 = threadIdx.x; i4 < 3072; i4 += 512) {
    int k = i4 >> 10, rem = i4 & 1023;
    int d = rem >> 4, h4 = rem & 15;
    float4 v = ((const float4*)W)[i4];
    *(float4*)&w_s[d * 192 + k * 64 + h4 * 4] = v;
  }
  int rowbase = bid * 128;
  for (int i4 = threadIdx.x; i4 < 2048; i4 += 512) {
    int r = i4 >> 4, c4 = i4 & 15;
    int row = rowbase + r;
    float4 v = (row < N) ? ntload4(X + (size_t)row * 64 + c4 * 4)
                         : make_float4(0.f, 0.f, 0.f, 0.f);
    if (BNIN) {
      float4 sc = ((const float4*)scale)[c4];
      float4 sh = ((const float4*)shift)[c4];
      float a = v.x * sc.x + sh.x, b = v.y * sc.y + sh.y;
      float c = v.z * sc.z + sh.z, d = v.w * sc.w + sh.w;
      v.x = (a > 0.f) ? a : 0.01f * a;
      v.y = (b > 0.f) ? b : 0.01f * b;
      v.z = (c > 0.f) ? c : 0.01f * c;
      v.w = (d > 0.f) ? d : 0.01f * d;
    }
    *(float4*)&x_s[r * 64 + c4 * 4] = v;
  }
  __syncthreads();

  int lane = threadIdx.x & 63;
  int wid = threadIdx.x >> 6;
  int r0 = wid * 16;
  float bv = bias[lane];
  float acc[48];
#pragma unroll
  for (int r = 0; r < 16; ++r) {
    acc[r * 3 + 0] = bv;
    acc[r * 3 + 1] = 0.f;
    acc[r * 3 + 2] = 0.f;
  }

  for (int d4 = 0; d4 < 16; ++d4) {
    float w[12];
#pragma unroll
    for (int k = 0; k < 4; ++k)
#pragma unroll
      for (int j = 0; j < 3; ++j)
        w[k * 3 + j] = w_s[(d4 * 4 + k) * 192 + j * 64 + lane];
#pragma unroll
    for (int r = 0; r < 16; ++r) {
      float4 xv = *(const float4*)&x_s[(r0 + r) * 64 + d4 * 4];  // bcast
#pragma unroll
      for (int j = 0; j < 3; ++j) {
        float a = acc[r * 3 + j];
        a = fmaf(xv.x, w[0 * 3 + j], a);
        a = fmaf(xv.y, w[1 * 3 + j], a);
        a = fmaf(xv.z, w[2 * 3 + j], a);
        a = fmaf(xv.w, w[3 * 3 + j], a);
        acc[r * 3 + j] = a;
      }
    }
  }

#pragma unroll
  for (int r = 0; r < 16; ++r) {
    int row = rowbase + r0 + r;
    if (row < N) {
      size_t o = (size_t)row * 64 + lane;
      __builtin_nontemporal_store(f2bf(acc[r * 3 + 0] - acc[r * 3 + 2]), &A02bf[o]);
      __builtin_nontemporal_store(f2bf(acc[r * 3 + 1]), &Y1bf[o]);
      Y2bf[o] = f2bf(dis[row] * acc[r * 3 + 2]);  // gather source: keep cached
    }
  }
}

// ---------- fused A: [gemmsc | count | sentinel-zero] ----------
__global__ __launch_bounds__(512) void k_fused_a(const float* __restrict__ X,
                                                 const float* __restrict__ W,
                                                 const float* __restrict__ bias,
                                                 float* __restrict__ S,
                                                 const int* __restrict__ row,
                                                 int* __restrict__ cnt,
                                                 unsigned short* __restrict__ Y2bf,
                                                 unsigned short* __restrict__ Vbf,
                                                 int N, int E, int NBG, int NC) {
  __shared__ float w_s[64 * 64];
  __shared__ float x_s[128 * 64];
  int bid = blockIdx.x;
  if (bid < NBG) {
    gemmsc_body(w_s, x_s, bid, X, W, bias, S, N);
  } else if (bid < NBG + NC) {
    int e = (bid - NBG) * 512 + threadIdx.x;
    if (e < E) atomicAdd(&cnt[row[e]], 1);
  } else {
    if (threadIdx.x < 64) {
      Y2bf[(size_t)N * 64 + threadIdx.x] = 0;
      Vbf[(size_t)N * 64 + threadIdx.x] = 0;
    }
  }
}

// ---------- fused B: [gemm192(l0) | fill] ----------
__global__ __launch_bounds__(512) void k_fused_b(const float* __restrict__ X,
                                                 const float* __restrict__ W,
                                                 const float* __restrict__ bias,
                                                 const float* __restrict__ dis,
                                                 unsigned short* __restrict__ A02bf,
                                                 unsigned short* __restrict__ Y1bf,
                                                 unsigned short* __restrict__ Y2bf,
                                                 const int* __restrict__ row,
                                                 const int* __restrict__ col,
                                                 int* __restrict__ cursor,
                                                 int* __restrict__ ccol,
                                                 int N, int E, int NBG) {
  __shared__ float w_s[64 * 192];
  __shared__ float x_s[128 * 64];
  int bid = blockIdx.x;
  if (bid < NBG) {
    gemm192_body<false>(w_s, x_s, bid, X, nullptr, nullptr, W, bias, dis,
                        A02bf, Y1bf, Y2bf, N);
  } else {
    int e = (bid - NBG) * 512 + threadIdx.x;
    if (e < E) {
      int r = row[e];
      int idx = atomicAdd(&cursor[r], 1);
      __builtin_nontemporal_store(col[e], &ccol[idx]);
    }
  }
}

// ---------- layer GEMM (l>=1, standalone) ----------
__global__ __launch_bounds__(512) void k_gemm192(const float* __restrict__ X,
                                                 const float* __restrict__ scale,
                                                 const float* __restrict__ shift,
                                                 const float* __restrict__ W,
                                                 const float* __restrict__ bias,
                                                 const float* __restrict__ dis,
                                                 unsigned short* __restrict__ A02bf,
                                                 unsigned short* __restrict__ Y1bf,
                                                 unsigned short* __restrict__ Y2bf,
                                                 int N) {
  __shared__ float w_s[64 * 192];
  __shared__ float x_s[128 * 64];
  gemm192_body<true>(w_s, x_s, blockIdx.x, X, scale, shift, W, bias, dis,
                     A02bf, Y1bf, Y2bf, N);
}

// ---------- prop v4: row-per-wave persistent, 16-deep, pre-scaled bf16 -------
// zbf PRE-SCALED: zbf[c] = bf16(dis[c]*z[c]);  (P z)[n] = -dis[n]*sum_c zbf[c]
// MODE 1: outbf[n] = bf16( dis[n]*(bf2f(inAbf[n]) - 2*dis[n]*acc) ); zeroes stats
// MODE 2: outC[n]  = bf2f(inAbf[n]) - dis[n]*acc  (+ fused BN stats)
template <int MODE>
__global__ __launch_bounds__(256) void k_prop4(const int* __restrict__ rowptr,
                                               const int* __restrict__ ccol,
                                               const float* __restrict__ dis,
                                               const unsigned short* __restrict__ zbf,
                                               const unsigned short* __restrict__ inAbf,
                                               unsigned short* __restrict__ outbf,
                                               float* __restrict__ outC,
                                               float* __restrict__ sums,
                                               float* __restrict__ sumsq,
                                               float* __restrict__ zstats,
                                               int N, int nwaves) {
  if (MODE == 1 && blockIdx.x == 0 && threadIdx.x < 128) zstats[threadIdx.x] = 0.f;
  int gw = blockIdx.x * 4 + (threadIdx.x >> 6);
  int lane = threadIdx.x & 63;
  int wid = threadIdx.x >> 6;
  float s = 0.f, s2 = 0.f;
  for (int n = gw; n < N; n += nwaves) {
    int beg = rowptr[n], end = rowptr[n + 1];
    float acc = 0.f;
    for (int j = beg; j < end; j += 16) {
      int cc[16];
#pragma unroll
      for (int u = 0; u < 16; ++u) {
        int jj = j + u;
        int c = ccol[jj];            // allocation padded by 16 -> safe load
        cc[u] = (jj < end) ? c : N;  // row N is zeroed
      }
      float vv[16];
#pragma unroll
      for (int u = 0; u < 16; ++u) vv[u] = bf2f(zbf[(size_t)cc[u] * 64 + lane]);
#pragma unroll
      for (int u = 0; u < 16; ++u) acc += vv[u];
    }
    float dn = dis[n];
    size_t o = (size_t)n * 64 + lane;
    float av = bf2f(__builtin_nontemporal_load(&inAbf[o]));
    if (MODE == 1) {
      float V = av - 2.f * dn * acc;
      outbf[o] = f2bf(dn * V);  // gather source for prop_b: keep cached
    } else {
      float v = av - dn * acc;
      __builtin_nontemporal_store(v, &outC[o]);
      s += v;
      s2 = fmaf(v, v, s2);
    }
  }
  if (MODE == 2) {
    __shared__ float red[2][4][64];
    red[0][wid][lane] = s;
    red[1][wid][lane] = s2;
    __syncthreads();
    if (wid == 0) {
      float a = red[0][0][lane] + red[0][1][lane] + red[0][2][lane] + red[0][3][lane];
      float b = red[1][0][lane] + red[1][1][lane] + red[1][2][lane] + red[1][3][lane];
      atomicAdd(&sums[lane], a);
      atomicAdd(&sumsq[lane], b);
    }
  }
}

__global__ void k_bncoef(const float* __restrict__ sums, const float* __restrict__ sumsq,
                         const float* __restrict__ g, const float* __restrict__ be,
                         float* __restrict__ scale, float* __restrict__ shift, int N) {
  int h = threadIdx.x;
  if (h >= 64) return;
  float inv_n = 1.0f / (float)N;
  float mu = sums[h] * inv_n;
  float var = sumsq[h] * inv_n - mu * mu;
  float sc = g[h] * rsqrtf(var + 1e-5f);
  scale[h] = sc;
  shift[h] = be[h] - mu * sc;
}

// ---------- pooling ----------
__global__ void k_poolinit(unsigned* __restrict__ pooled, int n) {
  int i = blockIdx.x * blockDim.x + threadIdx.x;
  if (i < n) pooled[i] = 0x007FFFFFu;  // key(-inf)
}

// fused: h = lrelu(bn(C)) + S; segment-max into pooled
__global__ void k_bnpool(const float* __restrict__ C, const float* __restrict__ scale,
                         const float* __restrict__ shift, const float* __restrict__ S,
                         const int* __restrict__ batch, unsigned* __restrict__ pooled,
                         int N) {
  int t = threadIdx.x;
  int h = t & 63;
  int rsub = t >> 6;
  int base = blockIdx.x * 64;
  float sc = scale[h], sh = shift[h];
  int cur_g = -1;
  unsigned best = 0;
  for (int i = 0; i < 16; ++i) {
    int n = base + rsub + 4 * i;
    if (n >= N) break;
    int g = batch[n];
    size_t o = (size_t)n * 64 + h;
    float a = __builtin_nontemporal_load(&C[o]) * sc + sh;
    a = (a > 0.f) ? a : 0.01f * a;
    a += __builtin_nontemporal_load(&S[o]);
    unsigned k = f2key(a);
    if (g != cur_g) {
      if (cur_g >= 0) atomicMax(&pooled[cur_g * 64 + h], best);
      cur_g = g;
      best = k;
    } else {
      best = max(best, k);
    }
  }
  if (cur_g >= 0) atomicMax(&pooled[cur_g * 64 + h], best);
}

__global__ void k_final(const unsigned* __restrict__ pooled, const float* __restrict__ w_lin,
                        const float* __restrict__ b_lin, float* __restrict__ out) {
  int g = blockIdx.x;
  int h = threadIdx.x;
  float v = key2f(pooled[g * 64 + h]) * w_lin[h];
  for (int off = 32; off > 0; off >>= 1) v += __shfl_down(v, off, 64);
  if (h == 0) out[g] = v + b_lin[0];
}

extern "C" void kernel_launch(void* const* d_in, const int* in_sizes, int n_in,
                              void* d_out, int out_size, void* d_ws, size_t ws_size,
                              hipStream_t stream) {
  const float* x = (const float*)d_in[0];
  const int* ei = (const int*)d_in[1];
  const int* batch = (const int*)d_in[2];
  const float* w1 = (const float*)d_in[3];
  const float* b1 = (const float*)d_in[4];
  const float* w2 = (const float*)d_in[5];
  const float* b2 = (const float*)d_in[6];
  const float* w3 = (const float*)d_in[7];
  const float* b3 = (const float*)d_in[8];
  const float* g1 = (const float*)d_in[9];
  const float* be1 = (const float*)d_in[10];
  const float* g2 = (const float*)d_in[11];
  const float* be2 = (const float*)d_in[12];
  const float* g3 = (const float*)d_in[13];
  const float* be3 = (const float*)d_in[14];
  const float* w_sc = (const float*)d_in[15];
  const float* b_sc = (const float*)d_in[16];
  const float* w_lin = (const float*)d_in[17];
  const float* b_lin = (const float*)d_in[18];

  int N = in_sizes[0] / 64;
  int E = in_sizes[1] / 2;
  int G = out_size;
  const int* row = ei;
  const int* col = ei + E;

  char* p = (char*)d_ws;
  auto carve = [&](size_t bytes) -> void* {
    void* r = (void*)p;
    p += (bytes + 255) & ~(size_t)255;
    return r;
  };
  int* cnt = (int*)carve((size_t)N * 4);
  float* dis = (float*)carve((size_t)N * 4);
  int* rowptr = (int*)carve((size_t)(N + 1) * 4);
  int* cursor = (int*)carve((size_t)N * 4);
  int* incl = (int*)carve((size_t)N * 4);
  int* bsum = (int*)carve(1024);
  int* bex = (int*)carve(1024);
  int* ccol = (int*)carve((size_t)(E + 64) * 4);   // +64 pad for batch over-read
  float* C = (float*)carve((size_t)N * 64 * 4);
  float* S = (float*)carve((size_t)N * 64 * 4);
  unsigned short* A02bf = (unsigned short*)carve((size_t)N * 64 * 2);
  unsigned short* Y1bf = (unsigned short*)carve((size_t)N * 64 * 2);
  unsigned short* Y2bf = (unsigned short*)carve((size_t)(N + 1) * 64 * 2);  // row N = 0
  unsigned short* Vbf = (unsigned short*)carve((size_t)(N + 1) * 64 * 2);   // row N = 0
  float* stats = (float*)carve(256 * 4);  // sums|sumsq|scale|shift
  unsigned* pooled = (unsigned*)carve((size_t)G * 64 * 4);

  int NBG = DIV_UP(N, 128);
  int NC = DIV_UP(E, 512);

  // ---- graph build + overlapped independent compute ----
  k_zero<<<DIV_UP(N, 256), 256, 0, stream>>>(cnt, N);
  // A: gemmsc || degree count || sentinel zero
  k_fused_a<<<NBG + NC + 1, 512, 0, stream>>>(x, w_sc, b_sc, S, row, cnt,
                                              Y2bf, Vbf, N, E, NBG, NC);
  k_dis<<<DIV_UP(N, 256), 256, 0, stream>>>(cnt, dis, N);
  int nb = DIV_UP(N, 1024);
  k_scan1<<<nb, 1024, 0, stream>>>(cnt, incl, bsum, N);
  k_scan2<<<1, 64, 0, stream>>>(bsum, bex, nb);
  k_scan3<<<DIV_UP(N, 256), 256, 0, stream>>>(incl, cnt, bex, rowptr, cursor, N, E);
  // B: gemm192(layer0) || CSR fill
  k_fused_b<<<NBG + NC, 512, 0, stream>>>(x, w1, b1, dis, A02bf, Y1bf, Y2bf,
                                          row, col, cursor, ccol, N, E, NBG);

  const float* Ws[3] = {w1, w2, w3};
  const float* bs[3] = {b1, b2, b3};
  const float* gs[3] = {g1, g2, g3};
  const float* bes[3] = {be1, be2, be3};

  const int PBLK = 2048;      // persistent blocks, 4 waves each
  const int NWAVE = PBLK * 4;
  for (int l = 0; l < 3; ++l) {
    if (l > 0)
      k_gemm192<<<NBG, 512, 0, stream>>>(C, stats + 128, stats + 192, Ws[l], bs[l],
                                         dis, A02bf, Y1bf, Y2bf, N);
    // Vbf = bf16( dis * (Y1 + 2*P*Y2) )   (also zeroes stats)
    k_prop4<1><<<PBLK, 256, 0, stream>>>(rowptr, ccol, dis, Y2bf, Y1bf,
                                         Vbf, nullptr, nullptr, nullptr, stats, N, NWAVE);
    // C = (Y0 - Y2) + P*V  (+ fused BN stats)
    k_prop4<2><<<PBLK, 256, 0, stream>>>(rowptr, ccol, dis, Vbf, A02bf,
                                         nullptr, C, stats, stats + 64, nullptr, N, NWAVE);
    k_bncoef<<<1, 64, 0, stream>>>(stats, stats + 64, gs[l], bes[l],
                                   stats + 128, stats + 192, N);
  }

  k_poolinit<<<DIV_UP(G * 64, 256), 256, 0, stream>>>(pooled, G * 64);
  k_bnpool<<<DIV_UP(N, 64), 256, 0, stream>>>(C, stats + 128, stats + 192, S, batch,
                                              pooled, N);
  k_final<<<G, 64, 0, stream>>>(pooled, w_lin, b_lin, (float*)d_out);
}